// Round 3
// baseline (286.551 us; speedup 1.0000x reference)
//
#include <hip/hip_runtime.h>
#include <math.h>

// z_t = a*x_t + b*z_{t-1}, z_{-1}=0 per row; a = 0.5*tanh(raw_a), b = tanh(raw_b).
// One 1024-thread block (16 waves) per row of T=8192. Wave w owns elems
// [w*512,(w+1)*512) as 2 sub-blocks of 256 (lane owns 4 contiguous floats ->
// unit-stride dwordx4 per instruction). Single load phase + single store phase
// per thread; block-level carry via a 16-wide LDS scan. No serial chunk loop.

typedef float f32x4 __attribute__((ext_vector_type(4)));

#define T_LEN 8192

__global__ __launch_bounds__(1024) void lincell_scan(
    const float* __restrict__ X,
    const float* __restrict__ pa,
    const float* __restrict__ pb,
    float* __restrict__ Z,
    int nrows)
{
    __shared__ float wsum[16];    // per-wave segment totals
    __shared__ float wcarry[16];  // exclusive carries into each wave

    const int row  = blockIdx.x;
    const int tid  = threadIdx.x;
    const int wave = tid >> 6;    // 0..15
    const int lane = tid & 63;
    if (row >= nrows) return;

    const float a  = 0.5f * tanhf(pa[0]);
    const float b  = tanhf(pb[0]);
    const float b2 = b * b;
    const float b3 = b2 * b;
    const float b4 = b2 * b2;                 // >= 0

    // cross-lane scan multipliers (segment decay m = b^4)
    float mstep[6];
#pragma unroll
    for (int k = 0; k < 6; ++k) {
        const int d = 1 << k;
        const int e = (lane + 1 < d) ? (lane + 1) : d;
        mstep[k] = powf(b4, (float)e);
    }
    const float b4lane = powf(b4, (float)lane);  // b^(4*lane)
    const float b256   = powf(b4, 64.0f);        // b^256 (sub-block decay)
    const float b512   = b256 * b256;            // b^512 (wave-segment decay)

    const f32x4* xrow = (const f32x4*)(X + (size_t)row * T_LEN);
    f32x4*       zrow = (f32x4*)(Z + (size_t)row * T_LEN);

    // ---- load: wave w covers vector indices [w*128, w*128+128) ----
    const int base = wave * 128 + lane;
    const f32x4 v0 = xrow[base];        // sub-block 0
    const f32x4 v1 = xrow[base + 64];   // sub-block 1

    // ---- in-lane serial scans (2 independent chains) ----
    float y0[2], y1[2], y2[2], y3[2], s[2];
    y0[0] = a * v0.x;
    y1[0] = fmaf(b, y0[0], a * v0.y);
    y2[0] = fmaf(b, y1[0], a * v0.z);
    y3[0] = fmaf(b, y2[0], a * v0.w);
    y0[1] = a * v1.x;
    y1[1] = fmaf(b, y0[1], a * v1.y);
    y2[1] = fmaf(b, y1[1], a * v1.z);
    y3[1] = fmaf(b, y2[1], a * v1.w);
    s[0] = y3[0];
    s[1] = y3[1];

    // ---- cross-lane affine scans (constant decay -> fma only) ----
#pragma unroll
    for (int k = 0; k < 6; ++k) {
#pragma unroll
        for (int j = 0; j < 2; ++j) {
            float t = __shfl_up(s[j], (unsigned)(1 << k), 64);
            t = (lane >= (1 << k)) ? t : 0.0f;
            s[j] = fmaf(mstep[k], t, s[j]);
        }
    }
    float excl[2], tot[2];
#pragma unroll
    for (int j = 0; j < 2; ++j) {
        float e = __shfl_up(s[j], 1u, 64);
        excl[j] = (lane >= 1) ? e : 0.0f;
        tot[j]  = __shfl(s[j], 63, 64);
    }

    // wave-segment total over 512 elems
    const float Wt = fmaf(b256, tot[0], tot[1]);
    if (lane == 0) wsum[wave] = Wt;
    __syncthreads();

    // ---- 16-wide exclusive affine scan of wave totals (wave 0 only) ----
    if (wave == 0) {
        float s16 = (lane < 16) ? wsum[lane] : 0.0f;
#pragma unroll
        for (int k = 0; k < 4; ++k) {
            const int d = 1 << k;
            const int e = (lane + 1 < d) ? (lane + 1) : d;
            const float m16 = powf(b512, (float)e);
            float t = __shfl_up(s16, (unsigned)d, 64);
            t = (lane >= d) ? t : 0.0f;
            s16 = fmaf(m16, t, s16);
        }
        float e16 = __shfl_up(s16, 1u, 64);
        e16 = (lane >= 1) ? e16 : 0.0f;
        if (lane < 16) wcarry[lane] = e16;
    }
    __syncthreads();

    // ---- apply carries and store ----
    const float carry = wcarry[wave];                  // z entering this wave's segment
    const float c0 = carry;
    const float c1 = fmaf(b256, carry, tot[0]);        // z entering sub-block 1

    const float pre0 = fmaf(b4lane, c0, excl[0]);
    const float pre1 = fmaf(b4lane, c1, excl[1]);

    f32x4 o0, o1;
    o0.x = fmaf(b,  pre0, y0[0]);
    o0.y = fmaf(b2, pre0, y1[0]);
    o0.z = fmaf(b3, pre0, y2[0]);
    o0.w = fmaf(b4, pre0, y3[0]);
    o1.x = fmaf(b,  pre1, y0[1]);
    o1.y = fmaf(b2, pre1, y1[1]);
    o1.z = fmaf(b3, pre1, y2[1]);
    o1.w = fmaf(b4, pre1, y3[1]);

    __builtin_nontemporal_store(o0, &zrow[base]);
    __builtin_nontemporal_store(o1, &zrow[base + 64]);
}

extern "C" void kernel_launch(void* const* d_in, const int* in_sizes, int n_in,
                              void* d_out, int out_size, void* d_ws, size_t ws_size,
                              hipStream_t stream) {
    const float* X  = (const float*)d_in[0];
    const float* pa = (const float*)d_in[1];
    const float* pb = (const float*)d_in[2];
    float* Z = (float*)d_out;

    const int nrows = in_sizes[0] / T_LEN;   // 4096
    lincell_scan<<<nrows, 1024, 0, stream>>>(X, pa, pb, Z, nrows);
}

// Round 4
// 234.594 us; speedup vs baseline: 1.2215x; 1.2215x over previous
//
#include <hip/hip_runtime.h>
#include <math.h>

// z_t = a*x_t + b*z_{t-1}, z_{-1}=0 per row; a = 0.5*tanh(raw_a), b = tanh(raw_b).
// One 1024-thread block (16 waves) per row of T=8192. Wave w owns 512 elems as
// 2 unit-stride float4 sub-blocks. Single load + single store phase, 2 barriers.
// ALL decay powers built by repeated squaring / binary decomposition — no powf.

typedef float f32x4 __attribute__((ext_vector_type(4)));

#define T_LEN 8192

__global__ __launch_bounds__(1024) void lincell_scan(
    const float* __restrict__ X,
    const float* __restrict__ pa,
    const float* __restrict__ pb,
    float* __restrict__ Z,
    int nrows)
{
    __shared__ float wsum[16];    // per-wave segment totals
    __shared__ float wcarry[16];  // exclusive carries into each wave

    const int row  = blockIdx.x;
    const int tid  = threadIdx.x;
    const int wave = tid >> 6;    // 0..15
    const int lane = tid & 63;
    if (row >= nrows) return;

    const float a  = 0.5f * tanhf(pa[0]);
    const float b  = tanhf(pb[0]);
    const float b2 = b * b;
    const float b3 = b2 * b;
    const float b4 = b2 * b2;     // segment decay m (>= 0)

    // repeated-squaring chain: m^(2^k) = b4^(2^k) = b^(4*2^k)
    const float m1  = b4;
    const float m2  = m1  * m1;
    const float m4  = m2  * m2;
    const float m8  = m4  * m4;
    const float m16 = m8  * m8;
    const float m32 = m16 * m16;
    const float m64 = m32 * m32;          // b4^64 = b^256
    const float mstep[6] = { m1, m2, m4, m8, m16, m32 };

    // b4^lane via binary decomposition of lane (6 selects + muls, no powf)
    float b4lane = 1.0f;
    b4lane *= (lane & 1)  ? m1  : 1.0f;
    b4lane *= (lane & 2)  ? m2  : 1.0f;
    b4lane *= (lane & 4)  ? m4  : 1.0f;
    b4lane *= (lane & 8)  ? m8  : 1.0f;
    b4lane *= (lane & 16) ? m16 : 1.0f;
    b4lane *= (lane & 32) ? m32 : 1.0f;

    const float b256 = m64;               // sub-block decay
    const float b512 = m64 * m64;         // wave-segment decay

    const f32x4* xrow = (const f32x4*)(X + (size_t)row * T_LEN);
    f32x4*       zrow = (f32x4*)(Z + (size_t)row * T_LEN);

    // ---- load: wave w covers vector indices [w*128, w*128+128) ----
    const int base = wave * 128 + lane;
    const f32x4 v0 = xrow[base];
    const f32x4 v1 = xrow[base + 64];

    // ---- in-lane serial scans (2 independent chains) ----
    float y0[2], y1[2], y2[2], y3[2], s[2];
    y0[0] = a * v0.x;
    y1[0] = fmaf(b, y0[0], a * v0.y);
    y2[0] = fmaf(b, y1[0], a * v0.z);
    y3[0] = fmaf(b, y2[0], a * v0.w);
    y0[1] = a * v1.x;
    y1[1] = fmaf(b, y0[1], a * v1.y);
    y2[1] = fmaf(b, y1[1], a * v1.z);
    y3[1] = fmaf(b, y2[1], a * v1.w);
    s[0] = y3[0];
    s[1] = y3[1];

    // ---- cross-lane affine scans: s_i += m^(2^k) * s_{i-2^k} ----
#pragma unroll
    for (int k = 0; k < 6; ++k) {
#pragma unroll
        for (int j = 0; j < 2; ++j) {
            float t = __shfl_up(s[j], (unsigned)(1 << k), 64);
            t = (lane >= (1 << k)) ? t : 0.0f;
            s[j] = fmaf(mstep[k], t, s[j]);
        }
    }
    float excl[2], tot[2];
#pragma unroll
    for (int j = 0; j < 2; ++j) {
        float e = __shfl_up(s[j], 1u, 64);
        excl[j] = (lane >= 1) ? e : 0.0f;
        tot[j]  = __shfl(s[j], 63, 64);
    }

    // wave-segment total over 512 elems
    const float Wt = fmaf(b256, tot[0], tot[1]);
    if (lane == 0) wsum[wave] = Wt;
    __syncthreads();

    // ---- 16-wide exclusive affine scan of wave totals (wave 0 only) ----
    if (wave == 0) {
        const float n1 = b512;
        const float n2 = n1 * n1;
        const float n4 = n2 * n2;
        const float n8 = n4 * n4;
        const float nstep[4] = { n1, n2, n4, n8 };
        float s16 = (lane < 16) ? wsum[lane] : 0.0f;
#pragma unroll
        for (int k = 0; k < 4; ++k) {
            float t = __shfl_up(s16, (unsigned)(1 << k), 64);
            t = (lane >= (1 << k)) ? t : 0.0f;
            s16 = fmaf(nstep[k], t, s16);
        }
        float e16 = __shfl_up(s16, 1u, 64);
        e16 = (lane >= 1) ? e16 : 0.0f;
        if (lane < 16) wcarry[lane] = e16;
    }
    __syncthreads();

    // ---- apply carries and store ----
    const float carry = wcarry[wave];              // z entering this wave's segment
    const float c0 = carry;
    const float c1 = fmaf(b256, carry, tot[0]);    // z entering sub-block 1

    const float pre0 = fmaf(b4lane, c0, excl[0]);
    const float pre1 = fmaf(b4lane, c1, excl[1]);

    f32x4 o0, o1;
    o0.x = fmaf(b,  pre0, y0[0]);
    o0.y = fmaf(b2, pre0, y1[0]);
    o0.z = fmaf(b3, pre0, y2[0]);
    o0.w = fmaf(b4, pre0, y3[0]);
    o1.x = fmaf(b,  pre1, y0[1]);
    o1.y = fmaf(b2, pre1, y1[1]);
    o1.z = fmaf(b3, pre1, y2[1]);
    o1.w = fmaf(b4, pre1, y3[1]);

    __builtin_nontemporal_store(o0, &zrow[base]);
    __builtin_nontemporal_store(o1, &zrow[base + 64]);
}

extern "C" void kernel_launch(void* const* d_in, const int* in_sizes, int n_in,
                              void* d_out, int out_size, void* d_ws, size_t ws_size,
                              hipStream_t stream) {
    const float* X  = (const float*)d_in[0];
    const float* pa = (const float*)d_in[1];
    const float* pb = (const float*)d_in[2];
    float* Z = (float*)d_out;

    const int nrows = in_sizes[0] / T_LEN;   // 4096
    lincell_scan<<<nrows, 1024, 0, stream>>>(X, pa, pb, Z, nrows);
}